// Round 3
// baseline (2978.886 us; speedup 1.0000x reference)
//
#include <hip/hip_runtime.h>

#define D 128
#define B_LOG 7            // 128 rows per bucket
#define ROWS_PB 128
#define MAX_NB 1024        // supports N <= 131072

// ---------------------------------------------------------------------------
// Kernel 1: fused dual GEMM
//   support1 = x @ W            (workspace)
//   out      = x @ W_skip + b   (initializes d_out; agg added by spmm_bucket)
// ---------------------------------------------------------------------------
__global__ __launch_bounds__(512) void dual_gemm_kernel(
    const float* __restrict__ x, const float* __restrict__ W,
    const float* __restrict__ Ws, const float* __restrict__ b,
    float* __restrict__ s1, float* __restrict__ out, int N)
{
    __shared__ float sW[D * D];
    __shared__ float sWs[D * D];

    const int t = threadIdx.x;
    for (int i = t * 4; i < D * D; i += 512 * 4) {
        *(float4*)&sW[i]  = *(const float4*)&W[i];
        *(float4*)&sWs[i] = *(const float4*)&Ws[i];
    }
    __syncthreads();

    const int lane   = t & 63;
    const int wave   = blockIdx.x * 8 + (t >> 6);
    const int nwaves = gridDim.x * 8;
    const int j      = lane * 2;
    const float2 bb  = *(const float2*)&b[j];

    for (int r0 = wave * 4; r0 < N; r0 += nwaves * 4) {
        float2 xr[4];
#pragma unroll
        for (int r = 0; r < 4; ++r)
            xr[r] = *(const float2*)&x[(size_t)(r0 + r) * D + j];

        float2 a1[4], a2[4];
#pragma unroll
        for (int r = 0; r < 4; ++r) {
            a1[r] = make_float2(0.f, 0.f);
            a2[r] = make_float2(0.f, 0.f);
        }

#pragma unroll 8
        for (int k = 0; k < D; ++k) {
            const float2 wk  = *(const float2*)&sW[k * D + j];
            const float2 wsk = *(const float2*)&sWs[k * D + j];
#pragma unroll
            for (int r = 0; r < 4; ++r) {
                const float xv = __shfl((k & 1) ? xr[r].y : xr[r].x, k >> 1, 64);
                a1[r].x = fmaf(xv, wk.x,  a1[r].x);
                a1[r].y = fmaf(xv, wk.y,  a1[r].y);
                a2[r].x = fmaf(xv, wsk.x, a2[r].x);
                a2[r].y = fmaf(xv, wsk.y, a2[r].y);
            }
        }

#pragma unroll
        for (int r = 0; r < 4; ++r) {
            *(float2*)&s1[(size_t)(r0 + r) * D + j]  = a1[r];
            *(float2*)&out[(size_t)(r0 + r) * D + j] =
                make_float2(a2[r].x + bb.x, a2[r].y + bb.y);
        }
    }
}

// ---------------------------------------------------------------------------
// Pass A: per-bucket histogram (LDS-staged: one global atomic per bucket/block)
// ---------------------------------------------------------------------------
__global__ __launch_bounds__(256) void bhist_kernel(
    const int* __restrict__ rows, int* __restrict__ bhist, int E, int nb)
{
    __shared__ int h[MAX_NB];
    const int t = threadIdx.x;
    for (int i = t; i < nb; i += 256) h[i] = 0;
    __syncthreads();

    int i = blockIdx.x * 256 + t;
    const int stride = gridDim.x * 256;
    for (; i < E; i += stride) atomicAdd(&h[rows[i] >> B_LOG], 1);
    __syncthreads();

    for (int i2 = t; i2 < nb; i2 += 256) {
        const int c = h[i2];
        if (c) atomicAdd(&bhist[i2], c);
    }
}

// ---------------------------------------------------------------------------
// Pass B: exclusive scan over nb bucket counts (single block, 4 elems/thread).
// Writes bptr[0..nb] and cursor copy bcur[0..nb-1].
// ---------------------------------------------------------------------------
__global__ __launch_bounds__(256) void bscan_kernel(
    const int* __restrict__ bhist, int* __restrict__ bptr,
    int* __restrict__ bcur, int nb)
{
    const int t = threadIdx.x;
    const int base_i = t * 4;
    int v[4];
#pragma unroll
    for (int k = 0; k < 4; ++k)
        v[k] = (base_i + k < nb) ? bhist[base_i + k] : 0;
    const int s = v[0] + v[1] + v[2] + v[3];

    const int lane = t & 63, wv = t >> 6;
    int sc = s;
    for (int o = 1; o < 64; o <<= 1) {
        const int u = __shfl_up(sc, o, 64);
        if (lane >= o) sc += u;
    }
    __shared__ int wsum[4];
    if (lane == 63) wsum[wv] = sc;
    __syncthreads();

    int wbase = 0;
    for (int w2 = 0; w2 < wv; ++w2) wbase += wsum[w2];
    int excl = wbase + (sc - s);
#pragma unroll
    for (int k = 0; k < 4; ++k) {
        if (base_i + k < nb) { bptr[base_i + k] = excl; bcur[base_i + k] = excl; }
        excl += v[k];
    }
    if (t == 255) bptr[nb] = wsum[0] + wsum[1] + wsum[2] + wsum[3];  // == E
}

// ---------------------------------------------------------------------------
// Pass C: partition edges into row-buckets. Per 8192-edge chunk: LDS hist ->
// one global cursor atomic per nonzero bucket -> slot assignment via LDS
// cursor. Writes per bucket per chunk are contiguous (~2x line amp vs 8x).
// Record: ((row & 127) << 20) | col, weight bits.
// ---------------------------------------------------------------------------
__global__ __launch_bounds__(256) void partition_kernel(
    const int* __restrict__ rows, const int* __restrict__ cols,
    const float* __restrict__ ew, int* __restrict__ bcur,
    int2* __restrict__ se, int E, int nb)
{
    __shared__ int h[MAX_NB];
    const int t = threadIdx.x;
    const int nchunks = (E + 8191) >> 13;

    for (int c = blockIdx.x; c < nchunks; c += gridDim.x) {
        const int ebeg = c << 13;
        const int eend = min(ebeg + 8192, E);

        for (int i = t; i < nb; i += 256) h[i] = 0;
        __syncthreads();

        for (int e = ebeg + t; e < eend; e += 256)
            atomicAdd(&h[rows[e] >> B_LOG], 1);
        __syncthreads();

        // allocate global space per bucket; repurpose h as the write cursor
        for (int i = t; i < nb; i += 256) {
            const int cnt = h[i];
            h[i] = cnt ? atomicAdd(&bcur[i], cnt) : 0;
        }
        __syncthreads();

        for (int e = ebeg + t; e < eend; e += 256) {
            const int r   = rows[e];
            const int bkt = r >> B_LOG;
            const int slot = atomicAdd(&h[bkt], 1);
            se[slot] = make_int2(((r & (ROWS_PB - 1)) << 20) | cols[e],
                                 __float_as_int(ew[e]));
        }
        __syncthreads();
    }
}

// ---------------------------------------------------------------------------
// Pass D: per-bucket SpMM with LDS accumulator (128 rows x 128 f32 = 64 KiB).
// Wave-per-edge, 4-deep unrolled gathers; lane l owns cols l and l+64
// (LDS bank = lane%32 -> conflict-free). One coalesced out+=acc pass at end.
// ---------------------------------------------------------------------------
__global__ __launch_bounds__(512) void spmm_bucket_kernel(
    const float* __restrict__ s1, const int* __restrict__ bptr,
    const int2* __restrict__ se, float* __restrict__ out, int N, int nb)
{
    __shared__ float acc[ROWS_PB * D];   // 64 KiB
    const int t = threadIdx.x, lane = t & 63, wv = t >> 6;

    for (int b = blockIdx.x; b < nb; b += gridDim.x) {
        for (int i = t * 4; i < ROWS_PB * D; i += 512 * 4)
            *(float4*)&acc[i] = make_float4(0.f, 0.f, 0.f, 0.f);
        __syncthreads();

        const int beg = bptr[b], end = bptr[b + 1];

        for (int e0 = beg + wv * 4; e0 < end; e0 += 32) {
            const int cnt = min(4, end - e0);
            int ro[4], cl[4];
            float ww[4], v0[4], v1[4];
#pragma unroll
            for (int k = 0; k < 4; ++k) {
                if (k < cnt) {
                    const int2 ed = se[e0 + k];
                    cl[k] = ed.x & 0xFFFFF;
                    ro[k] = ed.x >> 20;
                    ww[k] = __int_as_float(ed.y);
                    v0[k] = s1[(size_t)cl[k] * D + lane];
                    v1[k] = s1[(size_t)cl[k] * D + 64 + lane];
                }
            }
#pragma unroll
            for (int k = 0; k < 4; ++k) {
                if (k < cnt) {
                    atomicAdd(&acc[ro[k] * D + lane],      ww[k] * v0[k]);
                    atomicAdd(&acc[ro[k] * D + 64 + lane], ww[k] * v1[k]);
                }
            }
        }
        __syncthreads();

        const int r0 = b << B_LOG;
        const int nr = min(ROWS_PB, N - r0);
        for (int i = t; i < nr * 32; i += 512) {
            const int r  = i >> 5;
            const int c4 = (i & 31) << 2;
            float4 o = *(float4*)&out[(size_t)(r0 + r) * D + c4];
            const float4 a = *(const float4*)&acc[r * D + c4];
            o.x += a.x; o.y += a.y; o.z += a.z; o.w += a.w;
            *(float4*)&out[(size_t)(r0 + r) * D + c4] = o;
        }
        __syncthreads();
    }
}

// ---------------------------------------------------------------------------
// Fallback (ws too small / nb too large): edge-parallel atomic scatter.
// ---------------------------------------------------------------------------
__global__ __launch_bounds__(256) void spmm_edges_kernel(
    const float* __restrict__ s1, const int* __restrict__ rows,
    const int* __restrict__ cols, const float* __restrict__ ew,
    float* __restrict__ out, int E)
{
    const int lane = threadIdx.x & 63;
    const int wave = blockIdx.x * (blockDim.x >> 6) + (threadIdx.x >> 6);
    const int nw   = gridDim.x * (blockDim.x >> 6);
    const int j    = lane * 2;

    const int epw   = (E + nw - 1) / nw;
    const int e_beg = wave * epw;
    const int e_end = min(e_beg + epw, E);

    for (int e = e_beg; e < e_end; ++e) {
        const int   r = rows[e];
        const int   c = cols[e];
        const float w = ew[e];
        const float2 v = *(const float2*)&s1[(size_t)c * D + j];
        float* o = &out[(size_t)r * D + j];
        unsafeAtomicAdd(o,     w * v.x);
        unsafeAtomicAdd(o + 1, w * v.y);
    }
}

// ---------------------------------------------------------------------------
extern "C" void kernel_launch(void* const* d_in, const int* in_sizes, int n_in,
                              void* d_out, int out_size, void* d_ws, size_t ws_size,
                              hipStream_t stream) {
    const float* x    = (const float*)d_in[0];
    const int*   rows = (const int*)  d_in[1];
    const int*   cols = (const int*)  d_in[2];
    const float* ew   = (const float*)d_in[3];
    const float* W    = (const float*)d_in[4];
    const float* Ws   = (const float*)d_in[5];
    const float* b    = (const float*)d_in[6];
    float*       out  = (float*)d_out;

    const int N  = in_sizes[0] / D;
    const int E  = in_sizes[1];
    const int nb = (N + ROWS_PB - 1) >> B_LOG;

    // Workspace: s1 (N*D f32) | bhist nb | bptr nb+1 | bcur nb | pad | se E int2
    const size_t s1_bytes  = (size_t)N * D * sizeof(float);
    const size_t int_bytes = ((size_t)(3 * nb + 1) * 4 + 7) & ~(size_t)7;
    const size_t need      = s1_bytes + int_bytes + (size_t)E * 8;

    float* s1 = (float*)d_ws;

    // Dual GEMM initializes s1 and out(+skip+bias).
    dual_gemm_kernel<<<768, 512, 0, stream>>>(x, W, Ws, b, s1, out, N);

    if (ws_size >= need && nb <= MAX_NB) {
        int*  ibase = (int*)((char*)d_ws + s1_bytes);
        int*  bhist = ibase;                // nb
        int*  bptr  = ibase + nb;           // nb+1
        int*  bcur  = ibase + 2 * nb + 1;   // nb
        int2* se    = (int2*)((char*)d_ws + s1_bytes + int_bytes);

        hipMemsetAsync(bhist, 0, (size_t)nb * 4, stream);
        bhist_kernel    <<<256, 256, 0, stream>>>(rows, bhist, E, nb);
        bscan_kernel    <<<1,   256, 0, stream>>>(bhist, bptr, bcur, nb);
        const int nchunks = (E + 8191) >> 13;
        partition_kernel<<<min(nchunks, 1024), 256, 0, stream>>>(
            rows, cols, ew, bcur, se, E, nb);
        spmm_bucket_kernel<<<512, 512, 0, stream>>>(s1, bptr, se, out, N, nb);
    } else {
        spmm_edges_kernel<<<2048, 256, 0, stream>>>(s1, rows, cols, ew, out, E);
    }
}

// Round 4
// 830.699 us; speedup vs baseline: 3.5860x; 3.5860x over previous
//
#include <hip/hip_runtime.h>

#define D 128
#define B_LOG 7            // 128 rows per bucket
#define ROWS_PB 128
#define MAX_NB 1024        // supports N <= 131072

// ---------------------------------------------------------------------------
// Kernel 1: fused dual GEMM
//   support1 = x @ W            (workspace)
//   out      = x @ W_skip + b   (initializes d_out; agg added by spmm_csr)
// ---------------------------------------------------------------------------
__global__ __launch_bounds__(512) void dual_gemm_kernel(
    const float* __restrict__ x, const float* __restrict__ W,
    const float* __restrict__ Ws, const float* __restrict__ b,
    float* __restrict__ s1, float* __restrict__ out, int N)
{
    __shared__ float sW[D * D];
    __shared__ float sWs[D * D];

    const int t = threadIdx.x;
    for (int i = t * 4; i < D * D; i += 512 * 4) {
        *(float4*)&sW[i]  = *(const float4*)&W[i];
        *(float4*)&sWs[i] = *(const float4*)&Ws[i];
    }
    __syncthreads();

    const int lane   = t & 63;
    const int wave   = blockIdx.x * 8 + (t >> 6);
    const int nwaves = gridDim.x * 8;
    const int j      = lane * 2;
    const float2 bb  = *(const float2*)&b[j];

    for (int r0 = wave * 4; r0 < N; r0 += nwaves * 4) {
        float2 xr[4];
#pragma unroll
        for (int r = 0; r < 4; ++r)
            xr[r] = *(const float2*)&x[(size_t)(r0 + r) * D + j];

        float2 a1[4], a2[4];
#pragma unroll
        for (int r = 0; r < 4; ++r) {
            a1[r] = make_float2(0.f, 0.f);
            a2[r] = make_float2(0.f, 0.f);
        }

#pragma unroll 8
        for (int k = 0; k < D; ++k) {
            const float2 wk  = *(const float2*)&sW[k * D + j];
            const float2 wsk = *(const float2*)&sWs[k * D + j];
#pragma unroll
            for (int r = 0; r < 4; ++r) {
                const float xv = __shfl((k & 1) ? xr[r].y : xr[r].x, k >> 1, 64);
                a1[r].x = fmaf(xv, wk.x,  a1[r].x);
                a1[r].y = fmaf(xv, wk.y,  a1[r].y);
                a2[r].x = fmaf(xv, wsk.x, a2[r].x);
                a2[r].y = fmaf(xv, wsk.y, a2[r].y);
            }
        }

#pragma unroll
        for (int r = 0; r < 4; ++r) {
            *(float2*)&s1[(size_t)(r0 + r) * D + j]  = a1[r];
            *(float2*)&out[(size_t)(r0 + r) * D + j] =
                make_float2(a2[r].x + bb.x, a2[r].y + bb.y);
        }
    }
}

// ---------------------------------------------------------------------------
// Per-row histogram (3.2M global atomics on 400 KB L2-resident array)
// ---------------------------------------------------------------------------
__global__ __launch_bounds__(256) void hist_kernel(
    const int* __restrict__ rows, int* __restrict__ hist, int E)
{
    int i = blockIdx.x * blockDim.x + threadIdx.x;
    const int stride = gridDim.x * blockDim.x;
    for (; i < E; i += stride)
        atomicAdd(&hist[rows[i]], 1);
}

// ---------------------------------------------------------------------------
// Exclusive prefix sum over N counts (single block) -> rowptr[0..N]
// ---------------------------------------------------------------------------
__global__ __launch_bounds__(1024) void scan_kernel(
    const int* __restrict__ hist, int* __restrict__ rowptr, int N)
{
    __shared__ int part[1024];
    const int t = threadIdx.x;
    const int chunk = (N + 1023) / 1024;
    const int beg = t * chunk;
    const int end = min(beg + chunk, N);

    int s = 0;
    for (int i = beg; i < end; ++i) s += hist[i];
    part[t] = s;
    __syncthreads();

    for (int off = 1; off < 1024; off <<= 1) {
        int v = (t >= off) ? part[t - off] : 0;
        __syncthreads();
        part[t] += v;
        __syncthreads();
    }

    int excl = (t == 0) ? 0 : part[t - 1];
    for (int i = beg; i < end; ++i) {
        rowptr[i] = excl;
        excl += hist[i];
    }
    if (t == 1023) rowptr[N] = excl;   // == E
}

// ---------------------------------------------------------------------------
// cur[i] = rowptr[i << shift]  (cursor init: shift=B_LOG for buckets, 0 rows)
// ---------------------------------------------------------------------------
__global__ __launch_bounds__(256) void initcur_kernel(
    const int* __restrict__ rowptr, int* __restrict__ cur, int n, int shift)
{
    const int i = blockIdx.x * 256 + threadIdx.x;
    if (i < n) cur[i] = rowptr[i << shift];
}

// ---------------------------------------------------------------------------
// Pass 1 sort: partition edges into 128-row buckets. Per 8192-edge chunk:
// LDS hist -> one global cursor atomic per nonzero bucket -> slot assignment
// via LDS cursor. Writes per bucket per chunk are contiguous runs.
// Bucket cursors start at rowptr[b*128], so bucket ranges align with CSR.
// Record: ((row & 127) << 20) | col, weight bits.
// ---------------------------------------------------------------------------
__global__ __launch_bounds__(256) void partition_kernel(
    const int* __restrict__ rows, const int* __restrict__ cols,
    const float* __restrict__ ew, int* __restrict__ bcur,
    int2* __restrict__ se1, int E, int nb)
{
    __shared__ int h[MAX_NB];
    const int t = threadIdx.x;
    const int nchunks = (E + 8191) >> 13;

    for (int c = blockIdx.x; c < nchunks; c += gridDim.x) {
        const int ebeg = c << 13;
        const int eend = min(ebeg + 8192, E);

        for (int i = t; i < nb; i += 256) h[i] = 0;
        __syncthreads();

        for (int e = ebeg + t; e < eend; e += 256)
            atomicAdd(&h[rows[e] >> B_LOG], 1);
        __syncthreads();

        for (int i = t; i < nb; i += 256) {
            const int cnt = h[i];
            h[i] = cnt ? atomicAdd(&bcur[i], cnt) : 0;
        }
        __syncthreads();

        for (int e = ebeg + t; e < eend; e += 256) {
            const int r    = rows[e];
            const int bkt  = r >> B_LOG;
            const int slot = atomicAdd(&h[bkt], 1);
            se1[slot] = make_int2(((r & (ROWS_PB - 1)) << 20) | cols[e],
                                  __float_as_int(ew[e]));
        }
        __syncthreads();
    }
}

// ---------------------------------------------------------------------------
// Pass 2 sort: block-per-bucket counting sort se1 -> se2 (full row order).
// 128 LDS cursors preloaded from rowptr; writes land within the bucket's
// ~32 KB region -> L2 write-combines, amp ~1.
// ---------------------------------------------------------------------------
__global__ __launch_bounds__(256) void binsort_kernel(
    const int* __restrict__ rowptr, const int2* __restrict__ se1,
    int2* __restrict__ se2, int N)
{
    __shared__ int cur[ROWS_PB];
    const int t  = threadIdx.x;
    const int b  = blockIdx.x;
    const int r0 = b << B_LOG;
    const int nr = min(ROWS_PB, N - r0);

    if (t < nr) cur[t] = rowptr[r0 + t];
    __syncthreads();

    const int beg = rowptr[r0];
    const int end = rowptr[min(r0 + ROWS_PB, N)];

    for (int e = beg + t; e < end; e += 256) {
        const int2 rec = se1[e];
        const int  rl  = rec.x >> 20;
        const int  slot = atomicAdd(&cur[rl], 1);
        se2[slot] = rec;
    }
}

// ---------------------------------------------------------------------------
// SpMM: wave per row, no LDS, full occupancy, 8-deep unrolled gathers.
// Lane l owns cols 2l, 2l+1. One non-atomic out[r] += acc at the end.
// ---------------------------------------------------------------------------
__global__ __launch_bounds__(256) void spmm_csr_kernel(
    const float* __restrict__ s1, const int* __restrict__ rowptr,
    const int2* __restrict__ se, float* __restrict__ out, int N)
{
    const int lane = threadIdx.x & 63;
    const int wave = blockIdx.x * 4 + (threadIdx.x >> 6);
    const int nw   = gridDim.x * 4;
    const int j    = lane * 2;

    for (int r = wave; r < N; r += nw) {
        const int beg = rowptr[r];
        const int end = rowptr[r + 1];

        float2 acc = make_float2(0.f, 0.f);
        int e = beg;
        for (; e + 8 <= end; e += 8) {
            int2 ed[8];
#pragma unroll
            for (int k = 0; k < 8; ++k) ed[k] = se[e + k];
            float2 v[8];
#pragma unroll
            for (int k = 0; k < 8; ++k)
                v[k] = *(const float2*)&s1[(size_t)(ed[k].x & 0xFFFFF) * D + j];
#pragma unroll
            for (int k = 0; k < 8; ++k) {
                const float w = __int_as_float(ed[k].y);
                acc.x = fmaf(w, v[k].x, acc.x);
                acc.y = fmaf(w, v[k].y, acc.y);
            }
        }
        for (; e < end; ++e) {
            const int2 ev = se[e];
            const float2 v = *(const float2*)&s1[(size_t)(ev.x & 0xFFFFF) * D + j];
            const float w = __int_as_float(ev.y);
            acc.x = fmaf(w, v.x, acc.x);
            acc.y = fmaf(w, v.y, acc.y);
        }

        float2 o = *(float2*)&out[(size_t)r * D + j];
        o.x += acc.x;
        o.y += acc.y;
        *(float2*)&out[(size_t)r * D + j] = o;
    }
}

// ---------------------------------------------------------------------------
// Mid fallback: direct full scatter (round-2 style, 8x write amp but correct)
// ---------------------------------------------------------------------------
__global__ __launch_bounds__(256) void scatter_kernel(
    const int* __restrict__ rows, const int* __restrict__ cols,
    const float* __restrict__ ew, int* __restrict__ cur,
    int2* __restrict__ se, int E)
{
    int i = blockIdx.x * blockDim.x + threadIdx.x;
    const int stride = gridDim.x * blockDim.x;
    for (; i < E; i += stride) {
        const int r = rows[i];
        const int slot = atomicAdd(&cur[r], 1);
        se[slot] = make_int2(cols[i], __float_as_int(ew[i]));
    }
}

// ---------------------------------------------------------------------------
// Last fallback: edge-parallel atomic scatter.
// ---------------------------------------------------------------------------
__global__ __launch_bounds__(256) void spmm_edges_kernel(
    const float* __restrict__ s1, const int* __restrict__ rows,
    const int* __restrict__ cols, const float* __restrict__ ew,
    float* __restrict__ out, int E)
{
    const int lane = threadIdx.x & 63;
    const int wave = blockIdx.x * (blockDim.x >> 6) + (threadIdx.x >> 6);
    const int nw   = gridDim.x * (blockDim.x >> 6);
    const int j    = lane * 2;

    const int epw   = (E + nw - 1) / nw;
    const int e_beg = wave * epw;
    const int e_end = min(e_beg + epw, E);

    for (int e = e_beg; e < e_end; ++e) {
        const int   r = rows[e];
        const int   c = cols[e];
        const float w = ew[e];
        const float2 v = *(const float2*)&s1[(size_t)c * D + j];
        float* o = &out[(size_t)r * D + j];
        unsafeAtomicAdd(o,     w * v.x);
        unsafeAtomicAdd(o + 1, w * v.y);
    }
}

// ---------------------------------------------------------------------------
extern "C" void kernel_launch(void* const* d_in, const int* in_sizes, int n_in,
                              void* d_out, int out_size, void* d_ws, size_t ws_size,
                              hipStream_t stream) {
    const float* x    = (const float*)d_in[0];
    const int*   rows = (const int*)  d_in[1];
    const int*   cols = (const int*)  d_in[2];
    const float* ew   = (const float*)d_in[3];
    const float* W    = (const float*)d_in[4];
    const float* Ws   = (const float*)d_in[5];
    const float* b    = (const float*)d_in[6];
    float*       out  = (float*)d_out;

    const int N  = in_sizes[0] / D;
    const int E  = in_sizes[1];
    const int nb = (N + ROWS_PB - 1) >> B_LOG;

    // Workspace: s1 | hist N | rowptr N+1 | cur N | pad | se1 E | se2 E
    const size_t s1_bytes  = (size_t)N * D * sizeof(float);
    const size_t int_bytes = ((size_t)(3 * N + 1) * 4 + 7) & ~(size_t)7;
    const size_t need_mid  = s1_bytes + int_bytes + (size_t)E * 8;
    const size_t need_full = need_mid + (size_t)E * 8;

    float* s1 = (float*)d_ws;

    dual_gemm_kernel<<<768, 512, 0, stream>>>(x, W, Ws, b, s1, out, N);

    if (ws_size >= need_mid && nb <= MAX_NB) {
        int*  ibase  = (int*)((char*)d_ws + s1_bytes);
        int*  hist   = ibase;               // N
        int*  rowptr = ibase + N;           // N+1
        int*  cur    = ibase + 2 * N + 1;   // N (bucket cursors use first nb)
        int2* se1    = (int2*)((char*)d_ws + s1_bytes + int_bytes);
        int2* se2    = se1 + E;

        hipMemsetAsync(hist, 0, (size_t)N * 4, stream);
        hist_kernel<<<2048, 256, 0, stream>>>(rows, hist, E);
        scan_kernel<<<1, 1024, 0, stream>>>(hist, rowptr, N);

        if (ws_size >= need_full) {
            // bucket partition -> in-bucket counting sort -> CSR spmm
            initcur_kernel<<<(nb + 255) / 256, 256, 0, stream>>>(rowptr, cur, nb, B_LOG);
            const int nchunks = (E + 8191) >> 13;
            partition_kernel<<<min(nchunks, 1024), 256, 0, stream>>>(
                rows, cols, ew, cur, se1, E, nb);
            binsort_kernel<<<nb, 256, 0, stream>>>(rowptr, se1, se2, N);
            spmm_csr_kernel<<<2048, 256, 0, stream>>>(s1, rowptr, se2, out, N);
        } else {
            // direct full scatter (higher write amp), then CSR spmm
            initcur_kernel<<<(N + 255) / 256, 256, 0, stream>>>(rowptr, cur, N, 0);
            scatter_kernel<<<2048, 256, 0, stream>>>(rows, cols, ew, cur, se1, E);
            spmm_csr_kernel<<<2048, 256, 0, stream>>>(s1, rowptr, se1, out, N);
        }
    } else {
        spmm_edges_kernel<<<2048, 256, 0, stream>>>(s1, rows, cols, ew, out, E);
    }
}

// Round 5
// 450.445 us; speedup vs baseline: 6.6132x; 1.8442x over previous
//
#include <hip/hip_runtime.h>

#define D 128
#define B_LOG 7            // 128 rows per bucket
#define ROWS_PB 128
#define MAX_NB 1024        // supports N <= 131072

// round-to-nearest-even float -> bf16 bits
static __device__ __forceinline__ unsigned short f2bf(float f) {
    unsigned u = __float_as_uint(f);
    u += 0x7FFFu + ((u >> 16) & 1u);
    return (unsigned short)(u >> 16);
}

// ---------------------------------------------------------------------------
// Kernel 1: fused dual GEMM (fp32 math)
//   s1b = bf16(x @ W)           (workspace, bf16 storage halves gather bytes)
//   out = x @ W_skip + b        (fp32; agg added by spmm_csr)
// ---------------------------------------------------------------------------
__global__ __launch_bounds__(512) void dual_gemm_kernel(
    const float* __restrict__ x, const float* __restrict__ W,
    const float* __restrict__ Ws, const float* __restrict__ b,
    unsigned short* __restrict__ s1b, float* __restrict__ out, int N)
{
    __shared__ float sW[D * D];
    __shared__ float sWs[D * D];

    const int t = threadIdx.x;
    for (int i = t * 4; i < D * D; i += 512 * 4) {
        *(float4*)&sW[i]  = *(const float4*)&W[i];
        *(float4*)&sWs[i] = *(const float4*)&Ws[i];
    }
    __syncthreads();

    const int lane   = t & 63;
    const int wave   = blockIdx.x * 8 + (t >> 6);
    const int nwaves = gridDim.x * 8;
    const int j      = lane * 2;
    const float2 bb  = *(const float2*)&b[j];

    for (int r0 = wave * 4; r0 < N; r0 += nwaves * 4) {
        float2 xr[4];
#pragma unroll
        for (int r = 0; r < 4; ++r)
            xr[r] = *(const float2*)&x[(size_t)(r0 + r) * D + j];

        float2 a1[4], a2[4];
#pragma unroll
        for (int r = 0; r < 4; ++r) {
            a1[r] = make_float2(0.f, 0.f);
            a2[r] = make_float2(0.f, 0.f);
        }

#pragma unroll 8
        for (int k = 0; k < D; ++k) {
            const float2 wk  = *(const float2*)&sW[k * D + j];
            const float2 wsk = *(const float2*)&sWs[k * D + j];
#pragma unroll
            for (int r = 0; r < 4; ++r) {
                const float xv = __shfl((k & 1) ? xr[r].y : xr[r].x, k >> 1, 64);
                a1[r].x = fmaf(xv, wk.x,  a1[r].x);
                a1[r].y = fmaf(xv, wk.y,  a1[r].y);
                a2[r].x = fmaf(xv, wsk.x, a2[r].x);
                a2[r].y = fmaf(xv, wsk.y, a2[r].y);
            }
        }

#pragma unroll
        for (int r = 0; r < 4; ++r) {
            const unsigned pk = (unsigned)f2bf(a1[r].x) |
                                ((unsigned)f2bf(a1[r].y) << 16);
            *(unsigned*)&s1b[(size_t)(r0 + r) * D + j] = pk;
            *(float2*)&out[(size_t)(r0 + r) * D + j] =
                make_float2(a2[r].x + bb.x, a2[r].y + bb.y);
        }
    }
}

// ---------------------------------------------------------------------------
// Bucket-level histogram (LDS-staged: one global atomic per bucket per block)
// ---------------------------------------------------------------------------
__global__ __launch_bounds__(256) void bhist_kernel(
    const int* __restrict__ rows, int* __restrict__ bhist, int E, int nb)
{
    __shared__ int h[MAX_NB];
    const int t = threadIdx.x;
    for (int i = t; i < nb; i += 256) h[i] = 0;
    __syncthreads();

    int i = blockIdx.x * 256 + t;
    const int stride = gridDim.x * 256;
    for (; i < E; i += stride) atomicAdd(&h[rows[i] >> B_LOG], 1);
    __syncthreads();

    for (int i2 = t; i2 < nb; i2 += 256) {
        const int c = h[i2];
        if (c) atomicAdd(&bhist[i2], c);
    }
}

// ---------------------------------------------------------------------------
// Exclusive scan over nb bucket counts (single block, 4 elems/thread).
// Writes bptr[0..nb] and cursor copy bcur[0..nb-1].
// ---------------------------------------------------------------------------
__global__ __launch_bounds__(256) void bscan_kernel(
    const int* __restrict__ bhist, int* __restrict__ bptr,
    int* __restrict__ bcur, int nb)
{
    const int t = threadIdx.x;
    const int base_i = t * 4;
    int v[4];
#pragma unroll
    for (int k = 0; k < 4; ++k)
        v[k] = (base_i + k < nb) ? bhist[base_i + k] : 0;
    const int s = v[0] + v[1] + v[2] + v[3];

    const int lane = t & 63, wv = t >> 6;
    int sc = s;
    for (int o = 1; o < 64; o <<= 1) {
        const int u = __shfl_up(sc, o, 64);
        if (lane >= o) sc += u;
    }
    __shared__ int wsum[4];
    if (lane == 63) wsum[wv] = sc;
    __syncthreads();

    int wbase = 0;
    for (int w2 = 0; w2 < wv; ++w2) wbase += wsum[w2];
    int excl = wbase + (sc - s);
#pragma unroll
    for (int k = 0; k < 4; ++k) {
        if (base_i + k < nb) { bptr[base_i + k] = excl; bcur[base_i + k] = excl; }
        excl += v[k];
    }
    if (t == 255) bptr[nb] = wsum[0] + wsum[1] + wsum[2] + wsum[3];  // == E
}

// ---------------------------------------------------------------------------
// Pass 1 sort: partition edges into 128-row buckets (chunked, low write-amp).
// Record: ((row & 127) << 20) | col, weight bits.
// ---------------------------------------------------------------------------
__global__ __launch_bounds__(256) void partition_kernel(
    const int* __restrict__ rows, const int* __restrict__ cols,
    const float* __restrict__ ew, int* __restrict__ bcur,
    int2* __restrict__ se1, int E, int nb)
{
    __shared__ int h[MAX_NB];
    const int t = threadIdx.x;
    const int nchunks = (E + 8191) >> 13;

    for (int c = blockIdx.x; c < nchunks; c += gridDim.x) {
        const int ebeg = c << 13;
        const int eend = min(ebeg + 8192, E);

        for (int i = t; i < nb; i += 256) h[i] = 0;
        __syncthreads();

        for (int e = ebeg + t; e < eend; e += 256)
            atomicAdd(&h[rows[e] >> B_LOG], 1);
        __syncthreads();

        for (int i = t; i < nb; i += 256) {
            const int cnt = h[i];
            h[i] = cnt ? atomicAdd(&bcur[i], cnt) : 0;
        }
        __syncthreads();

        for (int e = ebeg + t; e < eend; e += 256) {
            const int r    = rows[e];
            const int bkt  = r >> B_LOG;
            const int slot = atomicAdd(&h[bkt], 1);
            se1[slot] = make_int2(((r & (ROWS_PB - 1)) << 20) | cols[e],
                                  __float_as_int(ew[e]));
        }
        __syncthreads();
    }
}

// ---------------------------------------------------------------------------
// Pass 2 sort: block-per-bucket counting sort se1 -> se2 AND per-row rowptr.
// LDS histogram of 128 row-locals -> LDS scan -> rowptr write + scatter.
// Replaces the global per-row hist + 100k-element single-block scan.
// ---------------------------------------------------------------------------
__global__ __launch_bounds__(256) void binsort_kernel(
    const int* __restrict__ bptr, const int2* __restrict__ se1,
    int2* __restrict__ se2, int* __restrict__ rowptr, int N, int E)
{
    __shared__ int cnt[ROWS_PB];
    __shared__ int pos[ROWS_PB];
    const int t  = threadIdx.x;
    const int b  = blockIdx.x;
    const int r0 = b << B_LOG;
    const int nr = min(ROWS_PB, N - r0);

    const int beg = bptr[b];
    const int end = bptr[b + 1];

    if (t < ROWS_PB) cnt[t] = 0;
    __syncthreads();

    for (int e = beg + t; e < end; e += 256)
        atomicAdd(&cnt[se1[e].x >> 20], 1);
    __syncthreads();

    if (t < ROWS_PB) pos[t] = cnt[t];
    __syncthreads();
#pragma unroll
    for (int off = 1; off < ROWS_PB; off <<= 1) {
        int v = (t < ROWS_PB && t >= off) ? pos[t - off] : 0;
        __syncthreads();
        if (t < ROWS_PB) pos[t] += v;
        __syncthreads();
    }
    // pos now inclusive; exclusive = pos - cnt. Reuse cnt[] as scatter cursor.
    if (t < ROWS_PB) {
        const int excl = beg + pos[t] - cnt[t];
        cnt[t] = excl;
        if (t < nr) rowptr[r0 + t] = excl;
    }
    if (t == 0 && r0 + nr == N) rowptr[N] = E;
    __syncthreads();

    for (int e = beg + t; e < end; e += 256) {
        const int2 rec = se1[e];
        const int  rl  = rec.x >> 20;
        const int  slot = atomicAdd(&cnt[rl], 1);
        se2[slot] = rec;
    }
}

// ---------------------------------------------------------------------------
// SpMM: wave per row, no LDS, full occupancy, 8-deep unrolled bf16 gathers.
// Lane l owns cols 2l, 2l+1 (one 4B uint = 2 bf16 per lane -> 256B/edge/wave).
// ---------------------------------------------------------------------------
__global__ __launch_bounds__(256) void spmm_csr_kernel(
    const unsigned short* __restrict__ s1b, const int* __restrict__ rowptr,
    const int2* __restrict__ se, float* __restrict__ out, int N)
{
    const int lane = threadIdx.x & 63;
    const int wave = blockIdx.x * 4 + (threadIdx.x >> 6);
    const int nw   = gridDim.x * 4;
    const int j    = lane * 2;

    for (int r = wave; r < N; r += nw) {
        const int beg = rowptr[r];
        const int end = rowptr[r + 1];

        float2 acc = make_float2(0.f, 0.f);
        int e = beg;
        for (; e + 8 <= end; e += 8) {
            int2 ed[8];
#pragma unroll
            for (int k = 0; k < 8; ++k) ed[k] = se[e + k];
            unsigned p[8];
#pragma unroll
            for (int k = 0; k < 8; ++k)
                p[k] = *(const unsigned*)&s1b[(size_t)(ed[k].x & 0xFFFFF) * D + j];
#pragma unroll
            for (int k = 0; k < 8; ++k) {
                const float w  = __int_as_float(ed[k].y);
                const float vx = __uint_as_float(p[k] << 16);
                const float vy = __uint_as_float(p[k] & 0xFFFF0000u);
                acc.x = fmaf(w, vx, acc.x);
                acc.y = fmaf(w, vy, acc.y);
            }
        }
        for (; e < end; ++e) {
            const int2 ev = se[e];
            const unsigned p = *(const unsigned*)&s1b[(size_t)(ev.x & 0xFFFFF) * D + j];
            const float w  = __int_as_float(ev.y);
            acc.x = fmaf(w, __uint_as_float(p << 16), acc.x);
            acc.y = fmaf(w, __uint_as_float(p & 0xFFFF0000u), acc.y);
        }

        float2 o = *(float2*)&out[(size_t)r * D + j];
        o.x += acc.x;
        o.y += acc.y;
        *(float2*)&out[(size_t)r * D + j] = o;
    }
}

// ---------------------------------------------------------------------------
// Fallback: edge-parallel atomic scatter (bf16 s1).
// ---------------------------------------------------------------------------
__global__ __launch_bounds__(256) void spmm_edges_kernel(
    const unsigned short* __restrict__ s1b, const int* __restrict__ rows,
    const int* __restrict__ cols, const float* __restrict__ ew,
    float* __restrict__ out, int E)
{
    const int lane = threadIdx.x & 63;
    const int wave = blockIdx.x * (blockDim.x >> 6) + (threadIdx.x >> 6);
    const int nw   = gridDim.x * (blockDim.x >> 6);
    const int j    = lane * 2;

    const int epw   = (E + nw - 1) / nw;
    const int e_beg = wave * epw;
    const int e_end = min(e_beg + epw, E);

    for (int e = e_beg; e < e_end; ++e) {
        const int   r = rows[e];
        const int   c = cols[e];
        const float w = ew[e];
        const unsigned p = *(const unsigned*)&s1b[(size_t)c * D + j];
        float* o = &out[(size_t)r * D + j];
        unsafeAtomicAdd(o,     w * __uint_as_float(p << 16));
        unsafeAtomicAdd(o + 1, w * __uint_as_float(p & 0xFFFF0000u));
    }
}

// ---------------------------------------------------------------------------
extern "C" void kernel_launch(void* const* d_in, const int* in_sizes, int n_in,
                              void* d_out, int out_size, void* d_ws, size_t ws_size,
                              hipStream_t stream) {
    const float* x    = (const float*)d_in[0];
    const int*   rows = (const int*)  d_in[1];
    const int*   cols = (const int*)  d_in[2];
    const float* ew   = (const float*)d_in[3];
    const float* W    = (const float*)d_in[4];
    const float* Ws   = (const float*)d_in[5];
    const float* b    = (const float*)d_in[6];
    float*       out  = (float*)d_out;

    const int N  = in_sizes[0] / D;
    const int E  = in_sizes[1];
    const int nb = (N + ROWS_PB - 1) >> B_LOG;

    // Workspace: s1b (N*D bf16) | bhist nb | bptr nb+1 | bcur nb | rowptr N+1
    //            | pad | se1 E int2 | se2 E int2
    const size_t s1_bytes  = ((size_t)N * D * 2 + 7) & ~(size_t)7;
    const size_t int_bytes = (((size_t)(3 * nb + N + 3)) * 4 + 7) & ~(size_t)7;
    const size_t need      = s1_bytes + int_bytes + (size_t)E * 16;

    unsigned short* s1b = (unsigned short*)d_ws;

    dual_gemm_kernel<<<768, 512, 0, stream>>>(x, W, Ws, b, s1b, out, N);

    if (ws_size >= need && nb <= MAX_NB) {
        int*  ibase  = (int*)((char*)d_ws + s1_bytes);
        int*  bhist  = ibase;                       // nb
        int*  bptr   = ibase + nb;                  // nb+1
        int*  bcur   = ibase + 2 * nb + 1;          // nb
        int*  rowptr = ibase + 3 * nb + 1;          // N+1
        int2* se1    = (int2*)((char*)d_ws + s1_bytes + int_bytes);
        int2* se2    = se1 + E;

        hipMemsetAsync(bhist, 0, (size_t)nb * 4, stream);
        bhist_kernel<<<256, 256, 0, stream>>>(rows, bhist, E, nb);
        bscan_kernel<<<1, 256, 0, stream>>>(bhist, bptr, bcur, nb);
        const int nchunks = (E + 8191) >> 13;
        partition_kernel<<<min(nchunks, 1024), 256, 0, stream>>>(
            rows, cols, ew, bcur, se1, E, nb);
        binsort_kernel<<<nb, 256, 0, stream>>>(bptr, se1, se2, rowptr, N, E);
        spmm_csr_kernel<<<2048, 256, 0, stream>>>(s1b, rowptr, se2, out, N);
    } else {
        spmm_edges_kernel<<<2048, 256, 0, stream>>>(s1b, rows, cols, ew, out, E);
    }
}

// Round 6
// 262.849 us; speedup vs baseline: 11.3331x; 1.7137x over previous
//
#include <hip/hip_runtime.h>

#define D 128
#define B_LOG 7            // 128 rows per bucket
#define ROWS_PB 128
#define MAX_NB 1024        // supports N <= 131072

typedef short bf16x8 __attribute__((ext_vector_type(8)));
typedef float f32x4  __attribute__((ext_vector_type(4)));

// round-to-nearest-even float -> bf16 bits
static __device__ __forceinline__ unsigned short f2bf(float f) {
    unsigned u = __float_as_uint(f);
    u += 0x7FFFu + ((u >> 16) & 1u);
    return (unsigned short)(u >> 16);
}

// ---------------------------------------------------------------------------
// Wt[mat][n][k] = bf16(Wmat[k][n])  (transpose so B-frags are contiguous-k)
// ---------------------------------------------------------------------------
__global__ __launch_bounds__(256) void wconv_kernel(
    const float* __restrict__ W, const float* __restrict__ Ws,
    short* __restrict__ Wt)
{
    const int idx = blockIdx.x * 256 + threadIdx.x;
    if (idx < 2 * D * D) {
        const int mat = idx >> 14;
        const int rem = idx & (D * D - 1);
        const int n = rem >> 7, k = rem & (D - 1);
        const float* src = mat ? Ws : W;
        Wt[idx] = (short)f2bf(src[k * D + n]);
    }
}

// ---------------------------------------------------------------------------
// MFMA dual GEMM: block = 64-row tile x 256 cols (W | Ws concat).
//   waves 0-1: s1b = bf16(x @ W); waves 2-3: out = x @ Ws + b (fp32)
// x-tile staged fp32->bf16 in LDS with XOR swizzle (T2: kills the 16-way
// bank conflict of stride-256B A-frag reads). B-frags in registers.
// Fragment maps (16x16x32_bf16): A/B lane l: m/n = l&15, k = (l>>4)*8 + i
// (contiguous); C/D: col = l&15, row = (l>>4)*4 + reg  [m89/m91/m92].
// ---------------------------------------------------------------------------
__global__ __launch_bounds__(256) void dual_gemm_mfma_kernel(
    const float* __restrict__ x, const short* __restrict__ Wt,
    const float* __restrict__ b, unsigned short* __restrict__ s1b,
    float* __restrict__ out, int N)
{
    __shared__ short sx[64 * D];   // 16 KiB bf16 x-tile

    const int t    = threadIdx.x;
    const int lane = t & 63;
    const int w    = t >> 6;

    // ---- B fragments: wave w owns concat-cols [w*64, w*64+64) ----
    const int bmat = w >> 1;
    const int bn0  = (w & 1) * 64 + (lane & 15);
    const int bk0  = (lane >> 4) * 8;
    bf16x8 Bf[4][4];   // [nf][ks]
#pragma unroll
    for (int nf = 0; nf < 4; ++nf)
#pragma unroll
        for (int ks = 0; ks < 4; ++ks)
            Bf[nf][ks] = *(const bf16x8*)&Wt[
                ((size_t)bmat * D + bn0 + nf * 16) * D + ks * 32 + bk0];

    float bias[4];
#pragma unroll
    for (int nf = 0; nf < 4; ++nf)
        bias[nf] = (w >= 2) ? b[(w - 2) * 64 + nf * 16 + (lane & 15)] : 0.f;

    const int ntiles = (N + 63) >> 6;
    const int trow = t >> 2;            // staging: row 0..63
    const int tk   = (t & 3) * 4;       // staging: float col base

    for (int rt = blockIdx.x; rt < ntiles; rt += gridDim.x) {
        const int r0 = rt << 6;
        __syncthreads();   // previous tile's compute done

        // ---- stage x-tile (fp32 -> bf16, swizzled) ----
        const int grow = min(r0 + trow, N - 1);
        const float* xrow = &x[(size_t)grow * D];
#pragma unroll
        for (int i = 0; i < 8; ++i) {
            const int k = tk + i * 16;
            const float4 v = *(const float4*)&xrow[k];
            const unsigned lo = (unsigned)f2bf(v.x) | ((unsigned)f2bf(v.y) << 16);
            const unsigned hi = (unsigned)f2bf(v.z) | ((unsigned)f2bf(v.w) << 16);
            unsigned byte = trow * 256 + k * 2;
            byte ^= (unsigned)((trow & 7) << 4);
            *(uint2*)((char*)sx + byte) = make_uint2(lo, hi);
        }
        __syncthreads();

        // ---- compute 64 MFMAs ----
        f32x4 acc[4][4];   // [mf][nf]
#pragma unroll
        for (int mf = 0; mf < 4; ++mf)
#pragma unroll
            for (int nf = 0; nf < 4; ++nf)
                acc[mf][nf] = (f32x4){0.f, 0.f, 0.f, 0.f};

#pragma unroll
        for (int ks = 0; ks < 4; ++ks) {
            bf16x8 Af[4];
#pragma unroll
            for (int mf = 0; mf < 4; ++mf) {
                const int row = mf * 16 + (lane & 15);
                unsigned byte = row * 256 + (ks * 32 + bk0) * 2;
                byte ^= (unsigned)((row & 7) << 4);
                Af[mf] = *(const bf16x8*)((const char*)sx + byte);
            }
#pragma unroll
            for (int mf = 0; mf < 4; ++mf)
#pragma unroll
                for (int nf = 0; nf < 4; ++nf)
                    acc[mf][nf] = __builtin_amdgcn_mfma_f32_16x16x32_bf16(
                        Af[mf], Bf[nf][ks], acc[mf][nf], 0, 0, 0);
        }

        // ---- store ----
#pragma unroll
        for (int mf = 0; mf < 4; ++mf) {
#pragma unroll
            for (int i = 0; i < 4; ++i) {
                const int row = r0 + mf * 16 + (lane >> 4) * 4 + i;
                if (row < N) {
                    if (w < 2) {
#pragma unroll
                        for (int nf = 0; nf < 4; ++nf) {
                            const int col = w * 64 + nf * 16 + (lane & 15);
                            s1b[(size_t)row * D + col] = f2bf(acc[mf][nf][i]);
                        }
                    } else {
#pragma unroll
                        for (int nf = 0; nf < 4; ++nf) {
                            const int col = (w - 2) * 64 + nf * 16 + (lane & 15);
                            out[(size_t)row * D + col] = acc[mf][nf][i] + bias[nf];
                        }
                    }
                }
            }
        }
    }
}

// ---------------------------------------------------------------------------
// Fallback vector dual GEMM (ws too small): fp32 math, bf16 s1 store.
// ---------------------------------------------------------------------------
__global__ __launch_bounds__(512) void dual_gemm_fb_kernel(
    const float* __restrict__ x, const float* __restrict__ W,
    const float* __restrict__ Ws, const float* __restrict__ b,
    unsigned short* __restrict__ s1b, float* __restrict__ out, int N)
{
    __shared__ float sW[D * D];
    __shared__ float sWs[D * D];

    const int t = threadIdx.x;
    for (int i = t * 4; i < D * D; i += 512 * 4) {
        *(float4*)&sW[i]  = *(const float4*)&W[i];
        *(float4*)&sWs[i] = *(const float4*)&Ws[i];
    }
    __syncthreads();

    const int lane   = t & 63;
    const int wave   = blockIdx.x * 8 + (t >> 6);
    const int nwaves = gridDim.x * 8;
    const int j      = lane * 2;
    const float2 bb  = *(const float2*)&b[j];

    for (int r0 = wave * 4; r0 < N; r0 += nwaves * 4) {
        float2 xr[4];
#pragma unroll
        for (int r = 0; r < 4; ++r)
            xr[r] = *(const float2*)&x[(size_t)(r0 + r) * D + j];

        float2 a1[4], a2[4];
#pragma unroll
        for (int r = 0; r < 4; ++r) {
            a1[r] = make_float2(0.f, 0.f);
            a2[r] = make_float2(0.f, 0.f);
        }

#pragma unroll 8
        for (int k = 0; k < D; ++k) {
            const float2 wk  = *(const float2*)&sW[k * D + j];
            const float2 wsk = *(const float2*)&sWs[k * D + j];
#pragma unroll
            for (int r = 0; r < 4; ++r) {
                const float xv = __shfl((k & 1) ? xr[r].y : xr[r].x, k >> 1, 64);
                a1[r].x = fmaf(xv, wk.x,  a1[r].x);
                a1[r].y = fmaf(xv, wk.y,  a1[r].y);
                a2[r].x = fmaf(xv, wsk.x, a2[r].x);
                a2[r].y = fmaf(xv, wsk.y, a2[r].y);
            }
        }

#pragma unroll
        for (int r = 0; r < 4; ++r) {
            const unsigned pk = (unsigned)f2bf(a1[r].x) |
                                ((unsigned)f2bf(a1[r].y) << 16);
            *(unsigned*)&s1b[(size_t)(r0 + r) * D + j] = pk;
            *(float2*)&out[(size_t)(r0 + r) * D + j] =
                make_float2(a2[r].x + bb.x, a2[r].y + bb.y);
        }
    }
}

// ---------------------------------------------------------------------------
// Bucket-level histogram (LDS-staged)
// ---------------------------------------------------------------------------
__global__ __launch_bounds__(256) void bhist_kernel(
    const int* __restrict__ rows, int* __restrict__ bhist, int E, int nb)
{
    __shared__ int h[MAX_NB];
    const int t = threadIdx.x;
    for (int i = t; i < nb; i += 256) h[i] = 0;
    __syncthreads();

    int i = blockIdx.x * 256 + t;
    const int stride = gridDim.x * 256;
    for (; i < E; i += stride) atomicAdd(&h[rows[i] >> B_LOG], 1);
    __syncthreads();

    for (int i2 = t; i2 < nb; i2 += 256) {
        const int c = h[i2];
        if (c) atomicAdd(&bhist[i2], c);
    }
}

// ---------------------------------------------------------------------------
// Exclusive scan over nb bucket counts -> bptr[0..nb], bcur copy
// ---------------------------------------------------------------------------
__global__ __launch_bounds__(256) void bscan_kernel(
    const int* __restrict__ bhist, int* __restrict__ bptr,
    int* __restrict__ bcur, int nb)
{
    const int t = threadIdx.x;
    const int base_i = t * 4;
    int v[4];
#pragma unroll
    for (int k = 0; k < 4; ++k)
        v[k] = (base_i + k < nb) ? bhist[base_i + k] : 0;
    const int s = v[0] + v[1] + v[2] + v[3];

    const int lane = t & 63, wv = t >> 6;
    int sc = s;
    for (int o = 1; o < 64; o <<= 1) {
        const int u = __shfl_up(sc, o, 64);
        if (lane >= o) sc += u;
    }
    __shared__ int wsum[4];
    if (lane == 63) wsum[wv] = sc;
    __syncthreads();

    int wbase = 0;
    for (int w2 = 0; w2 < wv; ++w2) wbase += wsum[w2];
    int excl = wbase + (sc - s);
#pragma unroll
    for (int k = 0; k < 4; ++k) {
        if (base_i + k < nb) { bptr[base_i + k] = excl; bcur[base_i + k] = excl; }
        excl += v[k];
    }
    if (t == 255) bptr[nb] = wsum[0] + wsum[1] + wsum[2] + wsum[3];  // == E
}

// ---------------------------------------------------------------------------
// Pass 1 sort: partition edges into 128-row buckets (chunked, low write-amp).
// ---------------------------------------------------------------------------
__global__ __launch_bounds__(256) void partition_kernel(
    const int* __restrict__ rows, const int* __restrict__ cols,
    const float* __restrict__ ew, int* __restrict__ bcur,
    int2* __restrict__ se1, int E, int nb)
{
    __shared__ int h[MAX_NB];
    const int t = threadIdx.x;
    const int nchunks = (E + 8191) >> 13;

    for (int c = blockIdx.x; c < nchunks; c += gridDim.x) {
        const int ebeg = c << 13;
        const int eend = min(ebeg + 8192, E);

        for (int i = t; i < nb; i += 256) h[i] = 0;
        __syncthreads();

        for (int e = ebeg + t; e < eend; e += 256)
            atomicAdd(&h[rows[e] >> B_LOG], 1);
        __syncthreads();

        for (int i = t; i < nb; i += 256) {
            const int cnt = h[i];
            h[i] = cnt ? atomicAdd(&bcur[i], cnt) : 0;
        }
        __syncthreads();

        for (int e = ebeg + t; e < eend; e += 256) {
            const int r    = rows[e];
            const int bkt  = r >> B_LOG;
            const int slot = atomicAdd(&h[bkt], 1);
            se1[slot] = make_int2(((r & (ROWS_PB - 1)) << 20) | cols[e],
                                  __float_as_int(ew[e]));
        }
        __syncthreads();
    }
}

// ---------------------------------------------------------------------------
// Pass 2 sort: block-per-bucket counting sort se1 -> se2 AND per-row rowptr.
// ---------------------------------------------------------------------------
__global__ __launch_bounds__(256) void binsort_kernel(
    const int* __restrict__ bptr, const int2* __restrict__ se1,
    int2* __restrict__ se2, int* __restrict__ rowptr, int N, int E)
{
    __shared__ int cnt[ROWS_PB];
    __shared__ int pos[ROWS_PB];
    const int t  = threadIdx.x;
    const int bk = blockIdx.x;
    const int r0 = bk << B_LOG;
    const int nr = min(ROWS_PB, N - r0);

    const int beg = bptr[bk];
    const int end = bptr[bk + 1];

    if (t < ROWS_PB) cnt[t] = 0;
    __syncthreads();

    for (int e = beg + t; e < end; e += 256)
        atomicAdd(&cnt[se1[e].x >> 20], 1);
    __syncthreads();

    if (t < ROWS_PB) pos[t] = cnt[t];
    __syncthreads();
#pragma unroll
    for (int off = 1; off < ROWS_PB; off <<= 1) {
        int v = (t < ROWS_PB && t >= off) ? pos[t - off] : 0;
        __syncthreads();
        if (t < ROWS_PB) pos[t] += v;
        __syncthreads();
    }
    if (t < ROWS_PB) {
        const int excl = beg + pos[t] - cnt[t];
        cnt[t] = excl;
        if (t < nr) rowptr[r0 + t] = excl;
    }
    if (t == 0 && r0 + nr == N) rowptr[N] = E;
    __syncthreads();

    for (int e = beg + t; e < end; e += 256) {
        const int2 rec = se1[e];
        const int  rl  = rec.x >> 20;
        const int  slot = atomicAdd(&cnt[rl], 1);
        se2[slot] = rec;
    }
}

// ---------------------------------------------------------------------------
// SpMM: wave per row, 8-deep unrolled bf16 gathers, no atomics.
// ---------------------------------------------------------------------------
__global__ __launch_bounds__(256) void spmm_csr_kernel(
    const unsigned short* __restrict__ s1b, const int* __restrict__ rowptr,
    const int2* __restrict__ se, float* __restrict__ out, int N)
{
    const int lane = threadIdx.x & 63;
    const int wave = blockIdx.x * 4 + (threadIdx.x >> 6);
    const int nw   = gridDim.x * 4;
    const int j    = lane * 2;

    for (int r = wave; r < N; r += nw) {
        const int beg = rowptr[r];
        const int end = rowptr[r + 1];

        float2 acc = make_float2(0.f, 0.f);
        int e = beg;
        for (; e + 8 <= end; e += 8) {
            int2 ed[8];
#pragma unroll
            for (int k = 0; k < 8; ++k) ed[k] = se[e + k];
            unsigned p[8];
#pragma unroll
            for (int k = 0; k < 8; ++k)
                p[k] = *(const unsigned*)&s1b[(size_t)(ed[k].x & 0xFFFFF) * D + j];
#pragma unroll
            for (int k = 0; k < 8; ++k) {
                const float w  = __int_as_float(ed[k].y);
                acc.x = fmaf(w, __uint_as_float(p[k] << 16), acc.x);
                acc.y = fmaf(w, __uint_as_float(p[k] & 0xFFFF0000u), acc.y);
            }
        }
        for (; e < end; ++e) {
            const int2 ev = se[e];
            const unsigned p = *(const unsigned*)&s1b[(size_t)(ev.x & 0xFFFFF) * D + j];
            const float w  = __int_as_float(ev.y);
            acc.x = fmaf(w, __uint_as_float(p << 16), acc.x);
            acc.y = fmaf(w, __uint_as_float(p & 0xFFFF0000u), acc.y);
        }

        float2 o = *(float2*)&out[(size_t)r * D + j];
        o.x += acc.x;
        o.y += acc.y;
        *(float2*)&out[(size_t)r * D + j] = o;
    }
}

// ---------------------------------------------------------------------------
// Fallback: edge-parallel atomic scatter (bf16 s1).
// ---------------------------------------------------------------------------
__global__ __launch_bounds__(256) void spmm_edges_kernel(
    const unsigned short* __restrict__ s1b, const int* __restrict__ rows,
    const int* __restrict__ cols, const float* __restrict__ ew,
    float* __restrict__ out, int E)
{
    const int lane = threadIdx.x & 63;
    const int wave = blockIdx.x * (blockDim.x >> 6) + (threadIdx.x >> 6);
    const int nw   = gridDim.x * (blockDim.x >> 6);
    const int j    = lane * 2;

    const int epw   = (E + nw - 1) / nw;
    const int e_beg = wave * epw;
    const int e_end = min(e_beg + epw, E);

    for (int e = e_beg; e < e_end; ++e) {
        const int   r = rows[e];
        const int   c = cols[e];
        const float w = ew[e];
        const unsigned p = *(const unsigned*)&s1b[(size_t)c * D + j];
        float* o = &out[(size_t)r * D + j];
        unsafeAtomicAdd(o,     w * __uint_as_float(p << 16));
        unsafeAtomicAdd(o + 1, w * __uint_as_float(p & 0xFFFF0000u));
    }
}

// ---------------------------------------------------------------------------
extern "C" void kernel_launch(void* const* d_in, const int* in_sizes, int n_in,
                              void* d_out, int out_size, void* d_ws, size_t ws_size,
                              hipStream_t stream) {
    const float* x    = (const float*)d_in[0];
    const int*   rows = (const int*)  d_in[1];
    const int*   cols = (const int*)  d_in[2];
    const float* ew   = (const float*)d_in[3];
    const float* W    = (const float*)d_in[4];
    const float* Ws   = (const float*)d_in[5];
    const float* b    = (const float*)d_in[6];
    float*       out  = (float*)d_out;

    const int N  = in_sizes[0] / D;
    const int E  = in_sizes[1];
    const int nb = (N + ROWS_PB - 1) >> B_LOG;

    // Workspace: s1b (N*D bf16) | Wt (2*D*D bf16) | bhist nb | bptr nb+1 |
    //            bcur nb | rowptr N+1 | pad | se1 E int2 | se2 E int2
    const size_t s1_bytes  = ((size_t)N * D * 2 + 15) & ~(size_t)15;
    const size_t wt_bytes  = (size_t)2 * D * D * 2;
    const size_t int_bytes = (((size_t)(3 * nb + N + 3)) * 4 + 7) & ~(size_t)7;
    const size_t need      = s1_bytes + wt_bytes + int_bytes + (size_t)E * 16;

    unsigned short* s1b = (unsigned short*)d_ws;

    if (ws_size >= need && nb <= MAX_NB) {
        short* Wt    = (short*)((char*)d_ws + s1_bytes);
        int*   ibase = (int*)((char*)d_ws + s1_bytes + wt_bytes);
        int*  bhist  = ibase;                       // nb
        int*  bptr   = ibase + nb;                  // nb+1
        int*  bcur   = ibase + 2 * nb + 1;          // nb
        int*  rowptr = ibase + 3 * nb + 1;          // N+1
        int2* se1    = (int2*)((char*)d_ws + s1_bytes + wt_bytes + int_bytes);
        int2* se2    = se1 + E;

        wconv_kernel<<<(2 * D * D + 255) / 256, 256, 0, stream>>>(W, Ws, Wt);
        dual_gemm_mfma_kernel<<<512, 256, 0, stream>>>(x, Wt, b, s1b, out, N);

        hipMemsetAsync(bhist, 0, (size_t)nb * 4, stream);
        bhist_kernel<<<256, 256, 0, stream>>>(rows, bhist, E, nb);
        bscan_kernel<<<1, 256, 0, stream>>>(bhist, bptr, bcur, nb);
        const int nchunks = (E + 8191) >> 13;
        partition_kernel<<<min(nchunks, 1024), 256, 0, stream>>>(
            rows, cols, ew, bcur, se1, E, nb);
        binsort_kernel<<<nb, 256, 0, stream>>>(bptr, se1, se2, rowptr, N, E);
        spmm_csr_kernel<<<2048, 256, 0, stream>>>(s1b, rowptr, se2, out, N);
    } else {
        dual_gemm_fb_kernel<<<768, 512, 0, stream>>>(x, W, Ws, b, s1b, out, N);
        spmm_edges_kernel<<<2048, 256, 0, stream>>>(s1b, rows, cols, ew, out, E);
    }
}